// Round 1
// baseline (270.343 us; speedup 1.0000x reference)
//
#include <hip/hip_runtime.h>
#include <hip/hip_bf16.h>

typedef __attribute__((ext_vector_type(8))) short short8;
typedef __attribute__((ext_vector_type(4))) float f32x4;
typedef __attribute__((ext_vector_type(4))) unsigned short u16x4;
typedef __attribute__((ext_vector_type(8))) unsigned short u16x8;

__device__ __forceinline__ unsigned short f2b(float f) {
  __hip_bfloat16 h = __float2bfloat16(f);
  return __builtin_bit_cast(unsigned short, h);
}

__device__ __forceinline__ void gload_lds16(const void* g, void* l) {
  __builtin_amdgcn_global_load_lds(
      (const __attribute__((address_space(1))) unsigned int*)g,
      (__attribute__((address_space(3))) unsigned int*)l, 16, 0, 0);
}

// ---------------- prepass: f32 -> bf16 linear convert ----------------
__global__ __launch_bounds__(256) void cvt_f32_bf16(const float* __restrict__ s,
                                                    unsigned short* __restrict__ d,
                                                    int n8) {
  int i = blockIdx.x * 256 + threadIdx.x;
  if (i >= n8) return;
  const f32x4* sp = (const f32x4*)s;
  f32x4 a = sp[2 * i];
  f32x4 b = sp[2 * i + 1];
  u16x8 o;
  o[0] = f2b(a[0]); o[1] = f2b(a[1]); o[2] = f2b(a[2]); o[3] = f2b(a[3]);
  o[4] = f2b(b[0]); o[5] = f2b(b[1]); o[6] = f2b(b[2]); o[7] = f2b(b[3]);
  ((u16x8*)d)[i] = o;
}

// ---------------- prepass: weight transpose+convert: Wt[n][k] = bf16(W[k][n]) ----
struct WtransParams {
  const float* w[6];
  unsigned short* wt[6];
};

__global__ __launch_bounds__(256) void wtrans(WtransParams p) {
  __shared__ float t[32][33];
  const int z = blockIdx.z;
  const float* W = p.w[z];
  unsigned short* Wt = p.wt[z];
  const int bx = blockIdx.x;  // n tile
  const int by = blockIdx.y;  // k tile
  const int tx = threadIdx.x, ty = threadIdx.y;
#pragma unroll
  for (int i = 0; i < 4; ++i)
    t[ty + 8 * i][tx] = W[(by * 32 + ty + 8 * i) * 1024 + bx * 32 + tx];
  __syncthreads();
#pragma unroll
  for (int i = 0; i < 4; ++i)
    Wt[(bx * 32 + ty + 8 * i) * 1024 + by * 32 + tx] = f2b(t[tx][ty + 8 * i]);
}

// ---------------- batched projection GEMM ----------------
// Y[m][n] = (A[m][:] @ W[:][n] + bias[n]) * scale, stored bf16 at
// out[((b*16+h)*S + s + s_off)*64 + d], n = h*64+d, b = m>>sshift, s = m&mask.
struct GemmJob {
  const unsigned short* Wt;  // [1024][1024] bf16, n-major
  const float* bias;         // [1024]
  unsigned short* out;
  int S;
  int s_off;
  float scale;
};
struct GemmParams {
  const unsigned short* A;  // [M][1024] bf16
  int sshift;               // log2 rows-per-batch
  GemmJob job[4];
};

__global__ __launch_bounds__(256) void gemm_qkv(GemmParams p) {
  __shared__ unsigned short As[128 * 64];
  __shared__ unsigned short Bs[128 * 64];
  const int tid = threadIdx.x;
  const int w = tid >> 6, lane = tid & 63;
  const int c = lane & 15, g = lane >> 4;
  const int z = blockIdx.z;
  const GemmJob j = p.job[z];
  const unsigned short* A = p.A;
  const unsigned short* B = j.Wt;
  const long arow0 = (long)blockIdx.y * 128;
  const long brow0 = (long)blockIdx.x * 128;

  f32x4 acc[4][4] = {};

  for (int kt = 0; kt < 16; ++kt) {
    __syncthreads();
#pragma unroll
    for (int i = 0; i < 4; ++i) {
      int ch = i * 256 + tid;
      int row = ch >> 3;
      int k8 = ((ch & 7) ^ (row & 7)) << 3;  // pre-swizzled source (T2)
      const unsigned short* ga = A + (arow0 + row) * 1024 + kt * 64 + k8;
      const unsigned short* gb = B + (brow0 + row) * 1024 + kt * 64 + k8;
      gload_lds16(ga, As + (i * 256 + w * 64) * 8);
      gload_lds16(gb, Bs + (i * 256 + w * 64) * 8);
    }
    __syncthreads();
#pragma unroll
    for (int kf = 0; kf < 2; ++kf) {
      short8 av[4], bv[4];
#pragma unroll
      for (int mf = 0; mf < 4; ++mf) {
        int row = (w >> 1) * 64 + mf * 16 + c;
        int byte = (row * 128 + (kf * 32 + g * 8) * 2) ^ ((row & 7) << 4);
        av[mf] = *(const short8*)((const char*)As + byte);
      }
#pragma unroll
      for (int nf = 0; nf < 4; ++nf) {
        int row = (w & 1) * 64 + nf * 16 + c;
        int byte = (row * 128 + (kf * 32 + g * 8) * 2) ^ ((row & 7) << 4);
        bv[nf] = *(const short8*)((const char*)Bs + byte);
      }
#pragma unroll
      for (int mf = 0; mf < 4; ++mf)
#pragma unroll
        for (int nf = 0; nf < 4; ++nf)
          acc[mf][nf] = __builtin_amdgcn_mfma_f32_16x16x32_bf16(av[mf], bv[nf],
                                                                acc[mf][nf], 0, 0, 0);
    }
  }

  // epilogue
  float biasv[4];
#pragma unroll
  for (int nf = 0; nf < 4; ++nf) {
    int n = (int)brow0 + (w & 1) * 64 + nf * 16 + c;
    biasv[nf] = j.bias[n];
  }
  const int smask = (1 << p.sshift) - 1;
#pragma unroll
  for (int mf = 0; mf < 4; ++mf) {
#pragma unroll
    for (int r = 0; r < 4; ++r) {
      int m = (int)arow0 + (w >> 1) * 64 + mf * 16 + g * 4 + r;
      int b_ = m >> p.sshift;
      int s = (m & smask) + j.s_off;
#pragma unroll
      for (int nf = 0; nf < 4; ++nf) {
        int n = (int)brow0 + (w & 1) * 64 + nf * 16 + c;
        int hh = n >> 6, dd = n & 63;
        float v = (acc[mf][nf][r] + biasv[nf]) * j.scale;
        j.out[(((long)b_ * 16 + hh) * j.S + s) * 64 + dd] = f2b(v);
      }
    }
  }
}

// ---------------- flash attention ----------------
// grid (18, 16, 2): tiles 0..15 word queries, 16..17 entity queries.
// 4 waves x 32 q-rows. KV tiles of 32 keys over S=2304 (word keys < 2048).
// Swapped QK^T: ST = mfma(K, Q) -> ST[key][q]; per-lane q col, 2-shuffle softmax.
__global__ __launch_bounds__(256) void attn_kernel(
    const unsigned short* __restrict__ qw2w, const unsigned short* __restrict__ qw2e,
    const unsigned short* __restrict__ qe2w, const unsigned short* __restrict__ qe2e,
    const unsigned short* __restrict__ Kg, const unsigned short* __restrict__ Vg,
    float* __restrict__ out) {
  __shared__ unsigned short Ksm[32 * 64];      // [key][d], swizzled
  __shared__ unsigned short Vtsm[64 * 32];     // [d][key], swizzled
  __shared__ unsigned short Plsm[4][32 * 32];  // per-wave P^T as [q][key], swizzled

  const int tid = threadIdx.x;
  const int w = tid >> 6, lane = tid & 63;
  const int c = lane & 15, g = lane >> 4;
  const int tile = blockIdx.x, h = blockIdx.y, b = blockIdx.z;
  const bool isw = tile < 16;
  const int Sq = isw ? 2048 : 256;
  const int q0 = (isw ? tile : tile - 16) * 128 + w * 32;
  const int bh = b * 16 + h;
  const unsigned short* Qa = (isw ? qw2w : qe2w) + ((long)bh * Sq + q0) * 64;
  const unsigned short* Qb = (isw ? qw2e : qe2e) + ((long)bh * Sq + q0) * 64;
  const unsigned short* Kb = Kg + (long)bh * 2304 * 64;
  const unsigned short* Vb = Vg + (long)bh * 2304 * 64;

  short8 qa[2][2], qb[2][2];  // [nf][kf]
#pragma unroll
  for (int nf = 0; nf < 2; ++nf)
#pragma unroll
    for (int kf = 0; kf < 2; ++kf) {
      qa[nf][kf] = *(const short8*)(Qa + (nf * 16 + c) * 64 + kf * 32 + g * 8);
      qb[nf][kf] = *(const short8*)(Qb + (nf * 16 + c) * 64 + kf * 32 + g * 8);
    }

  f32x4 o[4][2] = {};  // ctx^T frags: [mf over d][nf over q]
  float mrun[2] = {-INFINITY, -INFINITY};
  float lrun[2] = {0.f, 0.f};

  const int vkey = tid & 31, vdg = tid >> 5;

  auto step = [&](int it, short8(&q)[2][2]) {
    const unsigned short* Kt = Kb + it * 2048;
    const unsigned short* Vt = Vb + it * 2048;
    __syncthreads();  // previous tile's LDS reads complete
    {
      int key = tid >> 3;
      int k8 = ((tid & 7) ^ (key & 7)) << 3;
      gload_lds16(Kt + key * 64 + k8, Ksm + w * 512);
    }
    {
      short8 vv = *(const short8*)(Vt + vkey * 64 + vdg * 8);
#pragma unroll
      for (int jj = 0; jj < 8; ++jj) {
        int dd = vdg * 8 + jj;
        int byte = (dd * 64 + vkey * 2) ^ ((dd & 7) << 4);
        *(unsigned short*)((char*)Vtsm + byte) = (unsigned short)vv[jj];
      }
    }
    __syncthreads();  // staging complete (drains vmcnt+lgkmcnt)

    // ST[key][q] = K . Q^T
    f32x4 st[2][2] = {};  // [f over keys][nf over q]
#pragma unroll
    for (int kf = 0; kf < 2; ++kf) {
      short8 kfr[2];
#pragma unroll
      for (int f = 0; f < 2; ++f) {
        int row = f * 16 + c;
        int byte = (row * 128 + (kf * 32 + g * 8) * 2) ^ ((row & 7) << 4);
        kfr[f] = *(const short8*)((const char*)Ksm + byte);
      }
#pragma unroll
      for (int f = 0; f < 2; ++f)
#pragma unroll
        for (int nf = 0; nf < 2; ++nf)
          st[f][nf] = __builtin_amdgcn_mfma_f32_16x16x32_bf16(kfr[f], q[nf][kf],
                                                              st[f][nf], 0, 0, 0);
    }

    // online softmax (per q column = per lane group)
#pragma unroll
    for (int nf = 0; nf < 2; ++nf) {
      float tmax = st[0][nf][0];
#pragma unroll
      for (int f = 0; f < 2; ++f)
#pragma unroll
        for (int r = 0; r < 4; ++r) tmax = fmaxf(tmax, st[f][nf][r]);
      tmax = fmaxf(tmax, __shfl_xor(tmax, 16));
      tmax = fmaxf(tmax, __shfl_xor(tmax, 32));
      float mn = fmaxf(mrun[nf], tmax);
      float alpha = __expf(mrun[nf] - mn);
      mrun[nf] = mn;
      float pp[2][4];
      float ls = 0.f;
#pragma unroll
      for (int f = 0; f < 2; ++f)
#pragma unroll
        for (int r = 0; r < 4; ++r) {
          pp[f][r] = __expf(st[f][nf][r] - mn);
          ls += pp[f][r];
        }
      ls += __shfl_xor(ls, 16);
      ls += __shfl_xor(ls, 32);
      lrun[nf] = lrun[nf] * alpha + ls;
#pragma unroll
      for (int mf = 0; mf < 4; ++mf) o[mf][nf] *= alpha;
      // write P^T rows into per-wave LDS: Pl[q][key], keys 16f+4g+r
#pragma unroll
      for (int f = 0; f < 2; ++f) {
        u16x4 pk;
        pk[0] = f2b(pp[f][0]); pk[1] = f2b(pp[f][1]);
        pk[2] = f2b(pp[f][2]); pk[3] = f2b(pp[f][3]);
        int qrow = nf * 16 + c;
        int byte = (qrow * 64 + f * 32 + g * 8) ^ ((qrow & 7) << 4);
        *(u16x4*)((char*)Plsm[w] + byte) = pk;
      }
    }
    asm volatile("s_waitcnt lgkmcnt(0)" ::: "memory");  // wave-local Pl visibility

    // ctx^T += V^T . P^T
    short8 pb[2];
#pragma unroll
    for (int nf = 0; nf < 2; ++nf) {
      int qrow = nf * 16 + c;
      int byte = (qrow * 64 + g * 16) ^ ((qrow & 7) << 4);
      pb[nf] = *(const short8*)((const char*)Plsm[w] + byte);
    }
#pragma unroll
    for (int mf = 0; mf < 4; ++mf) {
      int dd = mf * 16 + c;
      int byte = (dd * 64 + g * 16) ^ ((dd & 7) << 4);
      short8 vf = *(const short8*)((const char*)Vtsm + byte);
#pragma unroll
      for (int nf = 0; nf < 2; ++nf)
        o[mf][nf] = __builtin_amdgcn_mfma_f32_16x16x32_bf16(vf, pb[nf],
                                                            o[mf][nf], 0, 0, 0);
    }
  };

  for (int it = 0; it < 64; ++it) step(it, qa);   // word keys
  for (int it = 64; it < 72; ++it) step(it, qb);  // entity keys

  const float inv0 = 1.f / lrun[0], inv1 = 1.f / lrun[1];
  float* ob = isw ? out + (((long)b * 2048 + q0) * 1024 + h * 64)
                  : out + (long)2 * 2048 * 1024 + (((long)b * 256 + q0) * 1024 + h * 64);
#pragma unroll
  for (int nf = 0; nf < 2; ++nf) {
    float inv = nf ? inv1 : inv0;
    int qr = nf * 16 + c;
#pragma unroll
    for (int mf = 0; mf < 4; ++mf) {
      f32x4 v = o[mf][nf] * inv;
      *(f32x4*)(ob + (long)qr * 1024 + mf * 16 + g * 4) = v;
    }
  }
}

// ---------------- host ----------------
extern "C" void kernel_launch(void* const* d_in, const int* in_sizes, int n_in,
                              void* d_out, int out_size, void* d_ws, size_t ws_size,
                              hipStream_t stream) {
  (void)in_sizes; (void)n_in; (void)out_size; (void)ws_size;
  const float* word = (const float*)d_in[0];
  const float* ent = (const float*)d_in[1];

  char* ws = (char*)d_ws;
  size_t off = 0;
  auto alloc = [&](size_t bytes) {
    void* p = ws + off;
    off += (bytes + 255) & ~(size_t)255;
    return p;
  };
  unsigned short* Xw = (unsigned short*)alloc(4096ull * 1024 * 2);
  unsigned short* Xe = (unsigned short*)alloc(512ull * 1024 * 2);
  unsigned short* Wt[6];
  for (int i = 0; i < 6; ++i) Wt[i] = (unsigned short*)alloc(1024ull * 1024 * 2);
  unsigned short* qw2w = (unsigned short*)alloc(2ull * 16 * 2048 * 64 * 2);
  unsigned short* qw2e = (unsigned short*)alloc(2ull * 16 * 2048 * 64 * 2);
  unsigned short* qe2w = (unsigned short*)alloc(2ull * 16 * 256 * 64 * 2);
  unsigned short* qe2e = (unsigned short*)alloc(2ull * 16 * 256 * 64 * 2);
  unsigned short* Kbuf = (unsigned short*)alloc(2ull * 16 * 2304 * 64 * 2);
  unsigned short* Vbuf = (unsigned short*)alloc(2ull * 16 * 2304 * 64 * 2);

  cvt_f32_bf16<<<2048, 256, 0, stream>>>(word, Xw, 524288);
  cvt_f32_bf16<<<256, 256, 0, stream>>>(ent, Xe, 65536);

  WtransParams wp;
  wp.w[0] = (const float*)d_in[2];   // Wq
  wp.w[1] = (const float*)d_in[4];   // Wk
  wp.w[2] = (const float*)d_in[6];   // Wv
  wp.w[3] = (const float*)d_in[8];   // Ww2e
  wp.w[4] = (const float*)d_in[10];  // We2w
  wp.w[5] = (const float*)d_in[12];  // We2e
  for (int i = 0; i < 6; ++i) wp.wt[i] = Wt[i];
  wtrans<<<dim3(32, 32, 6), dim3(32, 8), 0, stream>>>(wp);

  const float* bq = (const float*)d_in[3];
  const float* bk = (const float*)d_in[5];
  const float* bv = (const float*)d_in[7];
  const float* bw2e = (const float*)d_in[9];
  const float* be2w = (const float*)d_in[11];
  const float* be2e = (const float*)d_in[13];
  const float qs = 0.125f;  // 1/sqrt(64)

  GemmParams gw;
  gw.A = Xw;
  gw.sshift = 11;
  gw.job[0] = {Wt[0], bq, qw2w, 2048, 0, qs};
  gw.job[1] = {Wt[3], bw2e, qw2e, 2048, 0, qs};
  gw.job[2] = {Wt[1], bk, Kbuf, 2304, 0, 1.f};
  gw.job[3] = {Wt[2], bv, Vbuf, 2304, 0, 1.f};
  gemm_qkv<<<dim3(8, 32, 4), 256, 0, stream>>>(gw);

  GemmParams ge;
  ge.A = Xe;
  ge.sshift = 8;
  ge.job[0] = {Wt[4], be2w, qe2w, 256, 0, qs};
  ge.job[1] = {Wt[5], be2e, qe2e, 256, 0, qs};
  ge.job[2] = {Wt[1], bk, Kbuf, 2304, 2048, 1.f};
  ge.job[3] = {Wt[2], bv, Vbuf, 2304, 2048, 1.f};
  gemm_qkv<<<dim3(8, 4, 4), 256, 0, stream>>>(ge);

  attn_kernel<<<dim3(18, 16, 2), 256, 0, stream>>>(qw2w, qw2e, qe2w, qe2e, Kbuf,
                                                   Vbuf, (float*)d_out);
}

// Round 3
// 193.737 us; speedup vs baseline: 1.3954x; 1.3954x over previous
//
#include <hip/hip_runtime.h>
#include <hip/hip_bf16.h>

typedef __attribute__((ext_vector_type(8))) short short8;
typedef __attribute__((ext_vector_type(4))) float f32x4;
typedef __attribute__((ext_vector_type(16))) float f32x16;
typedef __attribute__((ext_vector_type(4))) unsigned short u16x4;
typedef __attribute__((ext_vector_type(8))) unsigned short u16x8;
typedef __attribute__((ext_vector_type(4))) unsigned int u32x4;

__device__ __forceinline__ unsigned short f2b(float f) {
  __hip_bfloat16 h = __float2bfloat16(f);
  return __builtin_bit_cast(unsigned short, h);
}

__device__ __forceinline__ void gload_lds16(const void* g, void* l) {
  __builtin_amdgcn_global_load_lds(
      (const __attribute__((address_space(1))) unsigned int*)g,
      (__attribute__((address_space(3))) unsigned int*)l, 16, 0, 0);
}

__device__ __forceinline__ f32x16 mfma32(short8 a, short8 b, f32x16 c) {
  return __builtin_amdgcn_mfma_f32_32x32x16_bf16(a, b, c, 0, 0, 0);
}

__device__ __forceinline__ unsigned int cvtpk(float a, float b) {
  unsigned int r;
  asm("v_cvt_pk_bf16_f32 %0, %1, %2" : "=v"(r) : "v"(a), "v"(b));
  return r;
}

// ---------------- prepass: f32 -> bf16 linear convert ----------------
__global__ __launch_bounds__(256) void cvt_f32_bf16(const float* __restrict__ s,
                                                    unsigned short* __restrict__ d,
                                                    int n8) {
  int i = blockIdx.x * 256 + threadIdx.x;
  if (i >= n8) return;
  const f32x4* sp = (const f32x4*)s;
  f32x4 a = sp[2 * i];
  f32x4 b = sp[2 * i + 1];
  u16x8 o;
  o[0] = f2b(a[0]); o[1] = f2b(a[1]); o[2] = f2b(a[2]); o[3] = f2b(a[3]);
  o[4] = f2b(b[0]); o[5] = f2b(b[1]); o[6] = f2b(b[2]); o[7] = f2b(b[3]);
  ((u16x8*)d)[i] = o;
}

// ------------- prepass: weight transpose+convert: Wt[n][k] = bf16(W[k][n]) ----
struct WtransParams {
  const float* w[6];
  unsigned short* wt[6];
};

__global__ __launch_bounds__(256) void wtrans(WtransParams p) {
  __shared__ float t[32][33];
  const int z = blockIdx.z;
  const float* W = p.w[z];
  unsigned short* Wt = p.wt[z];
  const int bx = blockIdx.x;
  const int by = blockIdx.y;
  const int tx = threadIdx.x, ty = threadIdx.y;
#pragma unroll
  for (int i = 0; i < 4; ++i)
    t[ty + 8 * i][tx] = W[(by * 32 + ty + 8 * i) * 1024 + bx * 32 + tx];
  __syncthreads();
#pragma unroll
  for (int i = 0; i < 4; ++i)
    Wt[(bx * 32 + ty + 8 * i) * 1024 + by * 32 + tx] = f2b(t[tx][ty + 8 * i]);
}

// ---------------- batched projection GEMM ----------------
struct GemmJob {
  const unsigned short* Wt;  // [1024][1024] bf16, n-major
  const float* bias;
  unsigned short* out;
  int S;
  int s_off;
  float scale;
  int trans;  // 0: out[bh][s][64]; 1: out[bh][64][2304] (V transposed)
};
struct GemmParams {
  const unsigned short* A;
  int sshift;
  GemmJob job[4];
};

__global__ __launch_bounds__(256) void gemm_qkv(GemmParams p) {
  __shared__ unsigned short As[128 * 64];
  __shared__ unsigned short Bs[128 * 64];
  const int tid = threadIdx.x;
  const int w = tid >> 6, lane = tid & 63;
  const int c = lane & 15, g = lane >> 4;
  const int z = blockIdx.z;
  const GemmJob j = p.job[z];
  const unsigned short* A = p.A;
  const unsigned short* B = j.Wt;
  const long arow0 = (long)blockIdx.y * 128;
  const long brow0 = (long)blockIdx.x * 128;

  f32x4 acc[4][4] = {};

  for (int kt = 0; kt < 16; ++kt) {
    __syncthreads();
#pragma unroll
    for (int i = 0; i < 4; ++i) {
      int ch = i * 256 + tid;
      int row = ch >> 3;
      int k8 = ((ch & 7) ^ (row & 7)) << 3;
      const unsigned short* ga = A + (arow0 + row) * 1024 + kt * 64 + k8;
      const unsigned short* gb = B + (brow0 + row) * 1024 + kt * 64 + k8;
      gload_lds16(ga, As + (i * 256 + w * 64) * 8);
      gload_lds16(gb, Bs + (i * 256 + w * 64) * 8);
    }
    __syncthreads();
#pragma unroll
    for (int kf = 0; kf < 2; ++kf) {
      short8 av[4], bv[4];
#pragma unroll
      for (int mf = 0; mf < 4; ++mf) {
        int row = (w >> 1) * 64 + mf * 16 + c;
        int byte = (row * 128 + (kf * 32 + g * 8) * 2) ^ ((row & 7) << 4);
        av[mf] = *(const short8*)((const char*)As + byte);
      }
#pragma unroll
      for (int nf = 0; nf < 4; ++nf) {
        int row = (w & 1) * 64 + nf * 16 + c;
        int byte = (row * 128 + (kf * 32 + g * 8) * 2) ^ ((row & 7) << 4);
        bv[nf] = *(const short8*)((const char*)Bs + byte);
      }
#pragma unroll
      for (int mf = 0; mf < 4; ++mf)
#pragma unroll
        for (int nf = 0; nf < 4; ++nf)
          acc[mf][nf] = __builtin_amdgcn_mfma_f32_16x16x32_bf16(av[mf], bv[nf],
                                                                acc[mf][nf], 0, 0, 0);
    }
  }

  float biasv[4];
#pragma unroll
  for (int nf = 0; nf < 4; ++nf) {
    int n = (int)brow0 + (w & 1) * 64 + nf * 16 + c;
    biasv[nf] = j.bias[n];
  }
  const int smask = (1 << p.sshift) - 1;
  if (j.trans) {
#pragma unroll
    for (int mf = 0; mf < 4; ++mf) {
      int m0 = (int)arow0 + (w >> 1) * 64 + mf * 16 + g * 4;
      int b_ = m0 >> p.sshift;
      int s = (m0 & smask) + j.s_off;
#pragma unroll
      for (int nf = 0; nf < 4; ++nf) {
        int n = (int)brow0 + (w & 1) * 64 + nf * 16 + c;
        int hh = n >> 6, dd = n & 63;
        u16x4 pv;
#pragma unroll
        for (int r = 0; r < 4; ++r)
          pv[r] = f2b((acc[mf][nf][r] + biasv[nf]) * j.scale);
        *(u16x4*)(j.out + (((long)b_ * 16 + hh) * 64 + dd) * 2304 + s) = pv;
      }
    }
  } else {
#pragma unroll
    for (int mf = 0; mf < 4; ++mf) {
#pragma unroll
      for (int r = 0; r < 4; ++r) {
        int m = (int)arow0 + (w >> 1) * 64 + mf * 16 + g * 4 + r;
        int b_ = m >> p.sshift;
        int s = (m & smask) + j.s_off;
#pragma unroll
        for (int nf = 0; nf < 4; ++nf) {
          int n = (int)brow0 + (w & 1) * 64 + nf * 16 + c;
          int hh = n >> 6, dd = n & 63;
          float v = (acc[mf][nf][r] + biasv[nf]) * j.scale;
          j.out[(((long)b_ * 16 + hh) * j.S + s) * 64 + dd] = f2b(v);
        }
      }
    }
  }
}

// ---------------- flash attention (32x32 MFMA, 64-key dbuf tiles) ----------------
// 576 blocks (XCD-grouped), 4 waves x 32 q-rows. One lane = one q column.
__global__ __launch_bounds__(256) void attn_kernel(
    const unsigned short* __restrict__ qw2w, const unsigned short* __restrict__ qw2e,
    const unsigned short* __restrict__ qe2w, const unsigned short* __restrict__ qe2e,
    const unsigned short* __restrict__ Kg, const unsigned short* __restrict__ Vtg,
    float* __restrict__ out) {
  __shared__ unsigned short smem[16384];  // 32 KiB: K dbuf [0,8KB), Vt dbuf [16KB,32KB)

  const int tid = threadIdx.x;
  const int w = tid >> 6, lane = tid & 63;
  const int l31 = lane & 31, hf = lane >> 5;

  // XCD-grouped bijective remap: 576 = 8 * 72
  const int flat = blockIdx.x;
  const int work = (flat & 7) * 72 + (flat >> 3);
  const int tile = work % 18;
  const int hb = work / 18;
  const int head = hb & 15, b = hb >> 4;

  const bool isw = tile < 16;
  const int Sq = isw ? 2048 : 256;
  const int q0 = (isw ? tile : tile - 16) * 128 + w * 32;
  const int bh = b * 16 + head;
  const unsigned short* Qa =
      (isw ? qw2w : qe2w) + ((long)bh * Sq + q0 + l31) * 64 + hf * 8;
  const unsigned short* Qb =
      (isw ? qw2e : qe2e) + ((long)bh * Sq + q0 + l31) * 64 + hf * 8;
  const unsigned short* Kb = Kg + (long)bh * 2304 * 64;
  const unsigned short* Vtb = Vtg + (long)bh * 64 * 2304;

  short8 qcur[4];
#pragma unroll
  for (int kf = 0; kf < 4; ++kf) qcur[kf] = *(const short8*)(Qa + kf * 16);

  f32x16 o[2] = {};
  float mrun = -1e30f;
  float lrun = 0.f;

  auto stage = [&](int t, int bufi) {
    const unsigned short* Kt = Kb + t * 4096;
    unsigned short* Klp = smem + bufi * 4096;
    unsigned short* Vlp = smem + 8192 + bufi * 4096;
#pragma unroll
    for (int i = 0; i < 2; ++i) {
      int ch = i * 256 + tid;
      int row = ch >> 3, c8 = ch & 7;
      int col = (c8 ^ (row & 7)) << 3;
      gload_lds16(Kt + row * 64 + col, Klp + (i * 256 + (tid & 192)) * 8);
      gload_lds16(Vtb + row * 2304 + t * 64 + col, Vlp + (i * 256 + (tid & 192)) * 8);
    }
  };

  stage(0, 0);
  __syncthreads();
  int cur = 0;

  for (int t = 0; t < 36; ++t) {
    if (t == 32) {
#pragma unroll
      for (int kf = 0; kf < 4; ++kf) qcur[kf] = *(const short8*)(Qb + kf * 16);
    }
    if (t + 1 < 36) stage(t + 1, cur ^ 1);

    const char* Kbase = (const char*)(smem + cur * 4096);
    const char* Vbase = (const char*)(smem + 8192 + cur * 4096);

    // QK^T: ST[key][q], 2 key-groups of 32
    f32x16 st[2] = {};
#pragma unroll
    for (int kg = 0; kg < 2; ++kg) {
      int row = kg * 32 + l31;
      int rb = (row * 128) | (hf * 16);
      int sw = (row & 7) << 4;
#pragma unroll
      for (int kf = 0; kf < 4; ++kf) {
        short8 kfr = *(const short8*)(Kbase + ((rb + kf * 32) ^ sw));
        st[kg] = mfma32(kfr, qcur[kf], st[kg]);
      }
    }

    // online softmax in exp2 domain (Q pre-scaled by 0.125*log2e)
    float tmax = st[0][0];
#pragma unroll
    for (int kg = 0; kg < 2; ++kg)
#pragma unroll
      for (int r = 0; r < 16; ++r) tmax = fmaxf(tmax, st[kg][r]);
    tmax = fmaxf(tmax, __shfl_xor(tmax, 32));
    if (!__all(tmax <= mrun + 8.f)) {
      float mn = fmaxf(mrun, tmax);
      float alpha = __builtin_amdgcn_exp2f(mrun - mn);
      mrun = mn;
      lrun *= alpha;
#pragma unroll
      for (int mf = 0; mf < 2; ++mf) o[mf] *= alpha;
    }
    float ls = 0.f;
#pragma unroll
    for (int kg = 0; kg < 2; ++kg)
#pragma unroll
      for (int r = 0; r < 16; ++r) {
        float pv = __builtin_amdgcn_exp2f(st[kg][r] - mrun);
        st[kg][r] = pv;
        ls += pv;
      }
    lrun += ls;

    // P -> bf16 B-frags in-register (cvt_pk + permlane32_swap), PV accumulate
#pragma unroll
    for (int kg = 0; kg < 2; ++kg)
#pragma unroll
      for (int hs = 0; hs < 2; ++hs) {
        const int rbase = hs * 8;
        unsigned int a0 = cvtpk(st[kg][rbase + 0], st[kg][rbase + 1]);
        unsigned int a1 = cvtpk(st[kg][rbase + 2], st[kg][rbase + 3]);
        unsigned int b0 = cvtpk(st[kg][rbase + 4], st[kg][rbase + 5]);
        unsigned int b1 = cvtpk(st[kg][rbase + 6], st[kg][rbase + 7]);
        asm("v_permlane32_swap_b32 %0, %1" : "+v"(a0), "+v"(b0));
        asm("v_permlane32_swap_b32 %0, %1" : "+v"(a1), "+v"(b1));
        u32x4 pw;
        pw[0] = a0; pw[1] = a1; pw[2] = b0; pw[3] = b1;
        short8 pf = __builtin_bit_cast(short8, pw);
        const int ks = kg * 2 + hs;
#pragma unroll
        for (int mf = 0; mf < 2; ++mf) {
          int row = mf * 32 + l31;
          int byte = ((row * 128) | (ks * 32 + hf * 16)) ^ ((row & 7) << 4);
          short8 vf = *(const short8*)(Vbase + byte);
          o[mf] = mfma32(vf, pf, o[mf]);
        }
      }

    __syncthreads();
    cur ^= 1;
  }

  // epilogue: normalize, transpose via per-wave LDS, coalesced f32 stores
  float ltot = lrun + __shfl_xor(lrun, 32);
  float inv = 1.f / ltot;

  float* E = (float*)smem + w * 2048;  // 32q x 64d per wave
#pragma unroll
  for (int mf = 0; mf < 2; ++mf)
#pragma unroll
    for (int rg = 0; rg < 4; ++rg) {
      int d0 = mf * 32 + rg * 8 + hf * 4;
      f32x4 v;
      v[0] = o[mf][rg * 4 + 0] * inv;
      v[1] = o[mf][rg * 4 + 1] * inv;
      v[2] = o[mf][rg * 4 + 2] * inv;
      v[3] = o[mf][rg * 4 + 3] * inv;
      *(f32x4*)(E + l31 * 64 + (d0 ^ ((l31 & 7) << 2))) = v;
    }

  float* ob = isw ? out + (((long)b * 2048 + q0) * 1024 + head * 64)
                  : out + (long)2 * 2048 * 1024 +
                        (((long)b * 256 + q0) * 1024 + head * 64);
#pragma unroll
  for (int i = 0; i < 8; ++i) {
    int qr = (lane >> 4) + i * 4;
    int dc = (lane & 15) * 4;
    f32x4 v = *(const f32x4*)(E + qr * 64 + (dc ^ ((qr & 7) << 2)));
    *(f32x4*)(ob + (long)qr * 1024 + dc) = v;
  }
}

// ---------------- host ----------------
extern "C" void kernel_launch(void* const* d_in, const int* in_sizes, int n_in,
                              void* d_out, int out_size, void* d_ws, size_t ws_size,
                              hipStream_t stream) {
  (void)in_sizes; (void)n_in; (void)out_size; (void)ws_size;
  const float* word = (const float*)d_in[0];
  const float* ent = (const float*)d_in[1];

  char* ws = (char*)d_ws;
  size_t off = 0;
  auto alloc = [&](size_t bytes) {
    void* p = ws + off;
    off += (bytes + 255) & ~(size_t)255;
    return p;
  };
  unsigned short* Xw = (unsigned short*)alloc(4096ull * 1024 * 2);
  unsigned short* Xe = (unsigned short*)alloc(512ull * 1024 * 2);
  unsigned short* Wt[6];
  for (int i = 0; i < 6; ++i) Wt[i] = (unsigned short*)alloc(1024ull * 1024 * 2);
  unsigned short* qw2w = (unsigned short*)alloc(2ull * 16 * 2048 * 64 * 2);
  unsigned short* qw2e = (unsigned short*)alloc(2ull * 16 * 2048 * 64 * 2);
  unsigned short* qe2w = (unsigned short*)alloc(2ull * 16 * 256 * 64 * 2);
  unsigned short* qe2e = (unsigned short*)alloc(2ull * 16 * 256 * 64 * 2);
  unsigned short* Kbuf = (unsigned short*)alloc(2ull * 16 * 2304 * 64 * 2);
  unsigned short* Vtbuf = (unsigned short*)alloc(2ull * 16 * 64 * 2304 * 2);

  cvt_f32_bf16<<<2048, 256, 0, stream>>>(word, Xw, 524288);
  cvt_f32_bf16<<<256, 256, 0, stream>>>(ent, Xe, 65536);

  WtransParams wp;
  wp.w[0] = (const float*)d_in[2];   // Wq
  wp.w[1] = (const float*)d_in[4];   // Wk
  wp.w[2] = (const float*)d_in[6];   // Wv
  wp.w[3] = (const float*)d_in[8];   // Ww2e
  wp.w[4] = (const float*)d_in[10];  // We2w
  wp.w[5] = (const float*)d_in[12];  // We2e
  for (int i = 0; i < 6; ++i) wp.wt[i] = Wt[i];
  wtrans<<<dim3(32, 32, 6), dim3(32, 8), 0, stream>>>(wp);

  const float* bq = (const float*)d_in[3];
  const float* bk = (const float*)d_in[5];
  const float* bv = (const float*)d_in[7];
  const float* bw2e = (const float*)d_in[9];
  const float* be2w = (const float*)d_in[11];
  const float* be2e = (const float*)d_in[13];
  const float qs = 0.125f * 1.44269504f;  // 1/sqrt(64) * log2(e): exp2-domain softmax

  GemmParams gw;
  gw.A = Xw;
  gw.sshift = 11;
  gw.job[0] = {Wt[0], bq, qw2w, 2048, 0, qs, 0};
  gw.job[1] = {Wt[3], bw2e, qw2e, 2048, 0, qs, 0};
  gw.job[2] = {Wt[1], bk, Kbuf, 2304, 0, 1.f, 0};
  gw.job[3] = {Wt[2], bv, Vtbuf, 2304, 0, 1.f, 1};
  gemm_qkv<<<dim3(8, 32, 4), 256, 0, stream>>>(gw);

  GemmParams ge;
  ge.A = Xe;
  ge.sshift = 8;
  ge.job[0] = {Wt[4], be2w, qe2w, 256, 0, qs, 0};
  ge.job[1] = {Wt[5], be2e, qe2e, 256, 0, qs, 0};
  ge.job[2] = {Wt[1], bk, Kbuf, 2304, 2048, 1.f, 0};
  ge.job[3] = {Wt[2], bv, Vtbuf, 2304, 2048, 1.f, 1};
  gemm_qkv<<<dim3(8, 4, 4), 256, 0, stream>>>(ge);

  attn_kernel<<<576, 256, 0, stream>>>(qw2w, qw2e, qe2w, qe2e, Kbuf, Vtbuf,
                                       (float*)d_out);
}

// Round 4
// 159.998 us; speedup vs baseline: 1.6897x; 1.2109x over previous
//
#include <hip/hip_runtime.h>
#include <hip/hip_bf16.h>

typedef __attribute__((ext_vector_type(8))) short short8;
typedef __attribute__((ext_vector_type(4))) float f32x4;
typedef __attribute__((ext_vector_type(16))) float f32x16;
typedef __attribute__((ext_vector_type(4))) unsigned short u16x4;
typedef __attribute__((ext_vector_type(8))) unsigned short u16x8;
typedef __attribute__((ext_vector_type(4))) unsigned int u32x4;

__device__ __forceinline__ unsigned short f2b(float f) {
  __hip_bfloat16 h = __float2bfloat16(f);
  return __builtin_bit_cast(unsigned short, h);
}

__device__ __forceinline__ void gload_lds16(const void* g, void* l) {
  __builtin_amdgcn_global_load_lds(
      (const __attribute__((address_space(1))) unsigned int*)g,
      (__attribute__((address_space(3))) unsigned int*)l, 16, 0, 0);
}

__device__ __forceinline__ f32x16 mfma32(short8 a, short8 b, f32x16 c) {
  return __builtin_amdgcn_mfma_f32_32x32x16_bf16(a, b, c, 0, 0, 0);
}

__device__ __forceinline__ unsigned int cvtpk(float a, float b) {
  unsigned int r;
  asm("v_cvt_pk_bf16_f32 %0, %1, %2" : "=v"(r) : "v"(a), "v"(b));
  return r;
}

// ---------------- prepass: f32 -> bf16 linear convert ----------------
__global__ __launch_bounds__(256) void cvt_f32_bf16(const float* __restrict__ s,
                                                    unsigned short* __restrict__ d,
                                                    int n8) {
  int i = blockIdx.x * 256 + threadIdx.x;
  if (i >= n8) return;
  const f32x4* sp = (const f32x4*)s;
  f32x4 a = sp[2 * i];
  f32x4 b = sp[2 * i + 1];
  u16x8 o;
  o[0] = f2b(a[0]); o[1] = f2b(a[1]); o[2] = f2b(a[2]); o[3] = f2b(a[3]);
  o[4] = f2b(b[0]); o[5] = f2b(b[1]); o[6] = f2b(b[2]); o[7] = f2b(b[3]);
  ((u16x8*)d)[i] = o;
}

// ------------- prepass: weight transpose+convert: Wt[n][k] = bf16(W[k][n]) ----
struct WtransParams {
  const float* w[6];
  unsigned short* wt[6];
};

__global__ __launch_bounds__(256) void wtrans(WtransParams p) {
  __shared__ float t[32][33];
  const int z = blockIdx.z;
  const float* W = p.w[z];
  unsigned short* Wt = p.wt[z];
  const int bx = blockIdx.x;
  const int by = blockIdx.y;
  const int tx = threadIdx.x, ty = threadIdx.y;
#pragma unroll
  for (int i = 0; i < 4; ++i)
    t[ty + 8 * i][tx] = W[(by * 32 + ty + 8 * i) * 1024 + bx * 32 + tx];
  __syncthreads();
#pragma unroll
  for (int i = 0; i < 4; ++i)
    Wt[(bx * 32 + ty + 8 * i) * 1024 + by * 32 + tx] = f2b(t[tx][ty + 8 * i]);
}

// ---------------- batched projection GEMM ----------------
struct GemmJob {
  const unsigned short* Wt;  // [1024][1024] bf16, n-major
  const float* bias;
  unsigned short* out;
  int S;
  int s_off;
  float scale;
  int trans;  // 0: out[bh][s][64]; 1: out[bh][64][2304] (V transposed)
};
struct GemmParams {
  const unsigned short* A;
  int sshift;
  GemmJob job[4];
};

__global__ __launch_bounds__(256) void gemm_qkv(GemmParams p) {
  __shared__ unsigned short As[128 * 64];
  __shared__ unsigned short Bs[128 * 64];
  const int tid = threadIdx.x;
  const int w = tid >> 6, lane = tid & 63;
  const int c = lane & 15, g = lane >> 4;
  const int z = blockIdx.z;
  const GemmJob j = p.job[z];
  const unsigned short* A = p.A;
  const unsigned short* B = j.Wt;
  const long arow0 = (long)blockIdx.y * 128;
  const long brow0 = (long)blockIdx.x * 128;

  f32x4 acc[4][4] = {};

  for (int kt = 0; kt < 16; ++kt) {
    __syncthreads();
#pragma unroll
    for (int i = 0; i < 4; ++i) {
      int ch = i * 256 + tid;
      int row = ch >> 3;
      int k8 = ((ch & 7) ^ (row & 7)) << 3;
      const unsigned short* ga = A + (arow0 + row) * 1024 + kt * 64 + k8;
      const unsigned short* gb = B + (brow0 + row) * 1024 + kt * 64 + k8;
      gload_lds16(ga, As + (i * 256 + w * 64) * 8);
      gload_lds16(gb, Bs + (i * 256 + w * 64) * 8);
    }
    __syncthreads();
#pragma unroll
    for (int kf = 0; kf < 2; ++kf) {
      short8 av[4], bv[4];
#pragma unroll
      for (int mf = 0; mf < 4; ++mf) {
        int row = (w >> 1) * 64 + mf * 16 + c;
        int byte = (row * 128 + (kf * 32 + g * 8) * 2) ^ ((row & 7) << 4);
        av[mf] = *(const short8*)((const char*)As + byte);
      }
#pragma unroll
      for (int nf = 0; nf < 4; ++nf) {
        int row = (w & 1) * 64 + nf * 16 + c;
        int byte = (row * 128 + (kf * 32 + g * 8) * 2) ^ ((row & 7) << 4);
        bv[nf] = *(const short8*)((const char*)Bs + byte);
      }
#pragma unroll
      for (int mf = 0; mf < 4; ++mf)
#pragma unroll
        for (int nf = 0; nf < 4; ++nf)
          acc[mf][nf] = __builtin_amdgcn_mfma_f32_16x16x32_bf16(av[mf], bv[nf],
                                                                acc[mf][nf], 0, 0, 0);
    }
  }

  float biasv[4];
#pragma unroll
  for (int nf = 0; nf < 4; ++nf) {
    int n = (int)brow0 + (w & 1) * 64 + nf * 16 + c;
    biasv[nf] = j.bias[n];
  }
  const int smask = (1 << p.sshift) - 1;
  if (j.trans) {
#pragma unroll
    for (int mf = 0; mf < 4; ++mf) {
      int m0 = (int)arow0 + (w >> 1) * 64 + mf * 16 + g * 4;
      int b_ = m0 >> p.sshift;
      int s = (m0 & smask) + j.s_off;
#pragma unroll
      for (int nf = 0; nf < 4; ++nf) {
        int n = (int)brow0 + (w & 1) * 64 + nf * 16 + c;
        int hh = n >> 6, dd = n & 63;
        u16x4 pv;
#pragma unroll
        for (int r = 0; r < 4; ++r)
          pv[r] = f2b((acc[mf][nf][r] + biasv[nf]) * j.scale);
        *(u16x4*)(j.out + (((long)b_ * 16 + hh) * 64 + dd) * 2304 + s) = pv;
      }
    }
  } else {
#pragma unroll
    for (int mf = 0; mf < 4; ++mf) {
#pragma unroll
      for (int r = 0; r < 4; ++r) {
        int m = (int)arow0 + (w >> 1) * 64 + mf * 16 + g * 4 + r;
        int b_ = m >> p.sshift;
        int s = (m & smask) + j.s_off;
#pragma unroll
        for (int nf = 0; nf < 4; ++nf) {
          int n = (int)brow0 + (w & 1) * 64 + nf * 16 + c;
          int hh = n >> 6, dd = n & 63;
          float v = (acc[mf][nf][r] + biasv[nf]) * j.scale;
          j.out[(((long)b_ * 16 + hh) * j.S + s) * 64 + dd] = f2b(v);
        }
      }
    }
  }
}

// ---------------- flash attention (key-split x2, fixed-max softmax) ----------
// 1152 blocks (XCD-grouped), 4 waves x 32 q-rows, part = half of the key range.
// Fixed softmax max M=16 (exp2 domain) => partial (o, l) additive across parts.
__global__ __launch_bounds__(256) void attn_kernel(
    const unsigned short* __restrict__ qw2w, const unsigned short* __restrict__ qw2e,
    const unsigned short* __restrict__ qe2w, const unsigned short* __restrict__ qe2e,
    const unsigned short* __restrict__ Kg, const unsigned short* __restrict__ Vtg,
    float* __restrict__ po0, float* __restrict__ po1, float* __restrict__ lbuf) {
  __shared__ unsigned short smem[16384];  // 32 KiB: K dbuf [0,8KB), Vt dbuf [16KB,32KB)

  const int tid = threadIdx.x;
  const int w = tid >> 6, lane = tid & 63;
  const int l31 = lane & 31, hf = lane >> 5;

  // XCD-grouped bijective remap: 1152 = 8 * 144; work = bh*36 + tile*2 + part
  const int flat = blockIdx.x;
  const int work = (flat & 7) * 144 + (flat >> 3);
  const int part = work & 1;
  const int tile = (work % 36) >> 1;
  const int hb = work / 36;
  const int head = hb & 15, b = hb >> 4;

  const bool isw = tile < 16;
  const int Sq = isw ? 2048 : 256;
  const int q0 = (isw ? tile : tile - 16) * 128 + w * 32;
  const int bh = b * 16 + head;
  const unsigned short* Qa =
      (isw ? qw2w : qe2w) + ((long)bh * Sq + q0 + l31) * 64 + hf * 8;
  const unsigned short* Qb =
      (isw ? qw2e : qe2e) + ((long)bh * Sq + q0 + l31) * 64 + hf * 8;
  const unsigned short* Kb = Kg + (long)bh * 2304 * 64;
  const unsigned short* Vtb = Vtg + (long)bh * 64 * 2304;

  short8 qcur[4];
#pragma unroll
  for (int kf = 0; kf < 4; ++kf) qcur[kf] = *(const short8*)(Qa + kf * 16);

  f32x16 o[2] = {};
  float lrun = 0.f;

  auto stage = [&](int t, int bufi) {
    const unsigned short* Kt = Kb + t * 4096;
    unsigned short* Klp = smem + bufi * 4096;
    unsigned short* Vlp = smem + 8192 + bufi * 4096;
#pragma unroll
    for (int i = 0; i < 2; ++i) {
      int ch = i * 256 + tid;
      int row = ch >> 3, c8 = ch & 7;
      int col = (c8 ^ (row & 7)) << 3;
      gload_lds16(Kt + row * 64 + col, Klp + (i * 256 + (tid & 192)) * 8);
      gload_lds16(Vtb + row * 2304 + t * 64 + col, Vlp + (i * 256 + (tid & 192)) * 8);
    }
  };

  const int t0 = part * 18, t1 = t0 + 18;
  stage(t0, 0);
  __syncthreads();
  int cur = 0;

  for (int t = t0; t < t1; ++t) {
    if (t == 32) {  // entity-key region: switch to the *2e query
#pragma unroll
      for (int kf = 0; kf < 4; ++kf) qcur[kf] = *(const short8*)(Qb + kf * 16);
    }
    if (t + 1 < t1) stage(t + 1, cur ^ 1);

    const char* Kbase = (const char*)(smem + cur * 4096);
    const char* Vbase = (const char*)(smem + 8192 + cur * 4096);

    // QK^T: ST[key][q], 2 key-groups of 32
    f32x16 st[2] = {};
#pragma unroll
    for (int kg = 0; kg < 2; ++kg) {
      int row = kg * 32 + l31;
      int rb = (row * 128) | (hf * 16);
      int sw = (row & 7) << 4;
#pragma unroll
      for (int kf = 0; kf < 4; ++kf) {
        short8 kfr = *(const short8*)(Kbase + ((rb + kf * 32) ^ sw));
        st[kg] = mfma32(kfr, qcur[kf], st[kg]);
      }
    }

    // fixed-max softmax in exp2 domain: P = exp2(st - 16)
    float ls = 0.f;
#pragma unroll
    for (int kg = 0; kg < 2; ++kg)
#pragma unroll
      for (int r = 0; r < 16; ++r) {
        float pv = __builtin_amdgcn_exp2f(st[kg][r] - 16.f);
        st[kg][r] = pv;
        ls += pv;
      }
    lrun += ls;

    // P -> bf16 B-frags in-register (cvt_pk + permlane32_swap), PV accumulate
#pragma unroll
    for (int kg = 0; kg < 2; ++kg)
#pragma unroll
      for (int hs = 0; hs < 2; ++hs) {
        const int rbase = hs * 8;
        unsigned int a0 = cvtpk(st[kg][rbase + 0], st[kg][rbase + 1]);
        unsigned int a1 = cvtpk(st[kg][rbase + 2], st[kg][rbase + 3]);
        unsigned int b0 = cvtpk(st[kg][rbase + 4], st[kg][rbase + 5]);
        unsigned int b1 = cvtpk(st[kg][rbase + 6], st[kg][rbase + 7]);
        asm("v_permlane32_swap_b32 %0, %1" : "+v"(a0), "+v"(b0));
        asm("v_permlane32_swap_b32 %0, %1" : "+v"(a1), "+v"(b1));
        u32x4 pw;
        pw[0] = a0; pw[1] = a1; pw[2] = b0; pw[3] = b1;
        short8 pf = __builtin_bit_cast(short8, pw);
        const int ks = kg * 2 + hs;
#pragma unroll
        for (int mf = 0; mf < 2; ++mf) {
          int row = mf * 32 + l31;
          int byte = ((row * 128) | (ks * 32 + hf * 16)) ^ ((row & 7) << 4);
          short8 vf = *(const short8*)(Vbase + byte);
          o[mf] = mfma32(vf, pf, o[mf]);
        }
      }

    __syncthreads();
    cur ^= 1;
  }

  // epilogue: combine lane halves, write UNNORMALIZED partial o + l
  float ltot = lrun + __shfl_xor(lrun, 32);

  const int sgb = (isw ? 0 : 2048) + q0;
  if (hf == 0) lbuf[(long)part * 73728 + bh * 2304 + sgb + l31] = ltot;

  float* E = (float*)smem + w * 2048;  // 32q x 64d per wave
#pragma unroll
  for (int mf = 0; mf < 2; ++mf)
#pragma unroll
    for (int rg = 0; rg < 4; ++rg) {
      int d0 = mf * 32 + rg * 8 + hf * 4;
      f32x4 v;
      v[0] = o[mf][rg * 4 + 0];
      v[1] = o[mf][rg * 4 + 1];
      v[2] = o[mf][rg * 4 + 2];
      v[3] = o[mf][rg * 4 + 3];
      *(f32x4*)(E + l31 * 64 + (d0 ^ ((l31 & 7) << 2))) = v;
    }

  float* po = part ? po1 : po0;
  float* ob = isw ? po + (((long)b * 2048 + q0) * 1024 + head * 64)
                  : po + (long)2 * 2048 * 1024 +
                        (((long)b * 256 + q0) * 1024 + head * 64);
#pragma unroll
  for (int i = 0; i < 8; ++i) {
    int qr = (lane >> 4) + i * 4;
    int dc = (lane & 15) * 4;
    f32x4 v = *(const f32x4*)(E + qr * 64 + (dc ^ ((qr & 7) << 2)));
    *(f32x4*)(ob + (long)qr * 1024 + dc) = v;
  }
}

// ---------------- merge: out = (o0 + o1) / (l0 + l1) ----------------
__global__ __launch_bounds__(256) void attn_merge(const float* __restrict__ po0,
                                                  const float* __restrict__ po1,
                                                  const float* __restrict__ lbuf,
                                                  float* __restrict__ out) {
  long i = ((long)blockIdx.x * 256 + threadIdx.x) * 4;
  if (i >= 4718592) return;
  int bh, sg;
  if (i < 4194304) {
    int b = (int)(i >> 21), s = (int)((i >> 10) & 2047), h = (int)((i >> 6) & 15);
    bh = b * 16 + h;
    sg = s;
  } else {
    long j = i - 4194304;
    int b = (int)(j >> 18), s = (int)((j >> 10) & 255), h = (int)((j >> 6) & 15);
    bh = b * 16 + h;
    sg = 2048 + s;
  }
  float l0 = lbuf[bh * 2304 + sg];
  float l1 = lbuf[73728 + bh * 2304 + sg];
  f32x4 a = *(const f32x4*)(po0 + i);
  f32x4 c = *(const f32x4*)(po1 + i);
  float inv = 1.f / (l0 + l1);
  f32x4 r = (a + c) * inv;
  *(f32x4*)(out + i) = r;
}

// ---------------- host ----------------
extern "C" void kernel_launch(void* const* d_in, const int* in_sizes, int n_in,
                              void* d_out, int out_size, void* d_ws, size_t ws_size,
                              hipStream_t stream) {
  (void)in_sizes; (void)n_in; (void)out_size; (void)ws_size;
  const float* word = (const float*)d_in[0];
  const float* ent = (const float*)d_in[1];

  char* ws = (char*)d_ws;
  size_t off = 0;
  auto alloc = [&](size_t bytes) {
    void* p = ws + off;
    off += (bytes + 255) & ~(size_t)255;
    return p;
  };
  // NOTE: po0 aliases [Xw, Xe, Wt) (22.0 MB front region) — those are dead by
  // the time attn_kernel writes po0 (all GEMMs complete first, same stream).
  unsigned short* Xw = (unsigned short*)alloc(4096ull * 1024 * 2);
  unsigned short* Xe = (unsigned short*)alloc(512ull * 1024 * 2);
  unsigned short* Wt[6];
  for (int i = 0; i < 6; ++i) Wt[i] = (unsigned short*)alloc(1024ull * 1024 * 2);
  unsigned short* qw2w = (unsigned short*)alloc(2ull * 16 * 2048 * 64 * 2);
  unsigned short* qw2e = (unsigned short*)alloc(2ull * 16 * 2048 * 64 * 2);
  unsigned short* qe2w = (unsigned short*)alloc(2ull * 16 * 256 * 64 * 2);
  unsigned short* qe2e = (unsigned short*)alloc(2ull * 16 * 256 * 64 * 2);
  unsigned short* Kbuf = (unsigned short*)alloc(2ull * 16 * 2304 * 64 * 2);
  unsigned short* Vtbuf = (unsigned short*)alloc(2ull * 16 * 64 * 2304 * 2);
  float* po1 = (float*)alloc(4718592ull * 4);
  float* lbuf = (float*)alloc(2ull * 73728 * 4);
  float* po0 = (float*)ws;  // aliases the dead prepass region

  cvt_f32_bf16<<<2048, 256, 0, stream>>>(word, Xw, 524288);
  cvt_f32_bf16<<<256, 256, 0, stream>>>(ent, Xe, 65536);

  WtransParams wp;
  wp.w[0] = (const float*)d_in[2];   // Wq
  wp.w[1] = (const float*)d_in[4];   // Wk
  wp.w[2] = (const float*)d_in[6];   // Wv
  wp.w[3] = (const float*)d_in[8];   // Ww2e
  wp.w[4] = (const float*)d_in[10];  // We2w
  wp.w[5] = (const float*)d_in[12];  // We2e
  for (int i = 0; i < 6; ++i) wp.wt[i] = Wt[i];
  wtrans<<<dim3(32, 32, 6), dim3(32, 8), 0, stream>>>(wp);

  const float* bq = (const float*)d_in[3];
  const float* bk = (const float*)d_in[5];
  const float* bv = (const float*)d_in[7];
  const float* bw2e = (const float*)d_in[9];
  const float* be2w = (const float*)d_in[11];
  const float* be2e = (const float*)d_in[13];
  const float qs = 0.125f * 1.44269504f;  // 1/sqrt(64) * log2(e): exp2-domain softmax

  GemmParams gw;
  gw.A = Xw;
  gw.sshift = 11;
  gw.job[0] = {Wt[0], bq, qw2w, 2048, 0, qs, 0};
  gw.job[1] = {Wt[3], bw2e, qw2e, 2048, 0, qs, 0};
  gw.job[2] = {Wt[1], bk, Kbuf, 2304, 0, 1.f, 0};
  gw.job[3] = {Wt[2], bv, Vtbuf, 2304, 0, 1.f, 1};
  gemm_qkv<<<dim3(8, 32, 4), 256, 0, stream>>>(gw);

  GemmParams ge;
  ge.A = Xe;
  ge.sshift = 8;
  ge.job[0] = {Wt[4], be2w, qe2w, 256, 0, qs, 0};
  ge.job[1] = {Wt[5], be2e, qe2e, 256, 0, qs, 0};
  ge.job[2] = {Wt[1], bk, Kbuf, 2304, 2048, 1.f, 0};
  ge.job[3] = {Wt[2], bv, Vtbuf, 2304, 2048, 1.f, 1};
  gemm_qkv<<<dim3(8, 4, 4), 256, 0, stream>>>(ge);

  attn_kernel<<<1152, 256, 0, stream>>>(qw2w, qw2e, qe2w, qe2e, Kbuf, Vtbuf,
                                        po0, po1, lbuf);
  attn_merge<<<4608, 256, 0, stream>>>(po0, po1, lbuf, (float*)d_out);
}

// Round 5
// 154.579 us; speedup vs baseline: 1.7489x; 1.0351x over previous
//
#include <hip/hip_runtime.h>
#include <hip/hip_bf16.h>

typedef __attribute__((ext_vector_type(8))) short short8;
typedef __attribute__((ext_vector_type(4))) float f32x4;
typedef __attribute__((ext_vector_type(16))) float f32x16;
typedef __attribute__((ext_vector_type(4))) unsigned short u16x4;
typedef __attribute__((ext_vector_type(8))) unsigned short u16x8;
typedef __attribute__((ext_vector_type(4))) unsigned int u32x4;

__device__ __forceinline__ unsigned short f2b(float f) {
  __hip_bfloat16 h = __float2bfloat16(f);
  return __builtin_bit_cast(unsigned short, h);
}

__device__ __forceinline__ void gload_lds16(const void* g, void* l) {
  __builtin_amdgcn_global_load_lds(
      (const __attribute__((address_space(1))) unsigned int*)g,
      (__attribute__((address_space(3))) unsigned int*)l, 16, 0, 0);
}

__device__ __forceinline__ f32x16 mfma32(short8 a, short8 b, f32x16 c) {
  return __builtin_amdgcn_mfma_f32_32x32x16_bf16(a, b, c, 0, 0, 0);
}

__device__ __forceinline__ unsigned int cvtpk(float a, float b) {
  unsigned int r;
  asm("v_cvt_pk_bf16_f32 %0, %1, %2" : "=v"(r) : "v"(a), "v"(b));
  return r;
}

// ---------------- prepass: f32 -> bf16 linear convert ----------------
__global__ __launch_bounds__(256) void cvt_f32_bf16(const float* __restrict__ s,
                                                    unsigned short* __restrict__ d,
                                                    int n8) {
  int i = blockIdx.x * 256 + threadIdx.x;
  if (i >= n8) return;
  const f32x4* sp = (const f32x4*)s;
  f32x4 a = sp[2 * i];
  f32x4 b = sp[2 * i + 1];
  u16x8 o;
  o[0] = f2b(a[0]); o[1] = f2b(a[1]); o[2] = f2b(a[2]); o[3] = f2b(a[3]);
  o[4] = f2b(b[0]); o[5] = f2b(b[1]); o[6] = f2b(b[2]); o[7] = f2b(b[3]);
  ((u16x8*)d)[i] = o;
}

// ------------- prepass: weight transpose+convert: Wt[n][k] = bf16(W[k][n]) ----
struct WtransParams {
  const float* w[6];
  unsigned short* wt[6];
};

__global__ __launch_bounds__(256) void wtrans(WtransParams p) {
  __shared__ float t[32][33];
  const int z = blockIdx.z;
  const float* W = p.w[z];
  unsigned short* Wt = p.wt[z];
  const int bx = blockIdx.x;
  const int by = blockIdx.y;
  const int tx = threadIdx.x, ty = threadIdx.y;
#pragma unroll
  for (int i = 0; i < 4; ++i)
    t[ty + 8 * i][tx] = W[(by * 32 + ty + 8 * i) * 1024 + bx * 32 + tx];
  __syncthreads();
#pragma unroll
  for (int i = 0; i < 4; ++i)
    Wt[(bx * 32 + ty + 8 * i) * 1024 + by * 32 + tx] = f2b(t[tx][ty + 8 * i]);
}

// ---------------- merged batched projection GEMM ----------------
// grid (8, 36, 4): y<32 -> word A (4096 rows), y>=32 -> entity A (512 rows).
// Job index = z (word) or z+4 (entity).
struct GemmJob {
  const unsigned short* Wt;  // [1024][1024] bf16, n-major
  const float* bias;
  unsigned short* out;
  int S;
  int s_off;
  int sshift;  // log2 rows-per-batch
  int trans;   // 0: out[bh][s][64]; 1: out[bh][64][2304] (V transposed)
  float scale;
};
struct Gemm2Params {
  const unsigned short* Aw;
  const unsigned short* Ae;
  GemmJob job[8];
};

__global__ __launch_bounds__(256) void gemm_qkv(Gemm2Params p) {
  __shared__ unsigned short As[128 * 64];
  __shared__ unsigned short Bs[128 * 64];
  const int tid = threadIdx.x;
  const int w = tid >> 6, lane = tid & 63;
  const int c = lane & 15, g = lane >> 4;
  const int z = blockIdx.z;
  const int y = blockIdx.y;
  const bool isw = y < 32;
  const GemmJob j = p.job[isw ? z : z + 4];
  const unsigned short* A = isw ? p.Aw : p.Ae;
  const long arow0 = (long)(isw ? y : y - 32) * 128;
  const unsigned short* B = j.Wt;
  const long brow0 = (long)blockIdx.x * 128;

  f32x4 acc[4][4] = {};

  for (int kt = 0; kt < 16; ++kt) {
    __syncthreads();
#pragma unroll
    for (int i = 0; i < 4; ++i) {
      int ch = i * 256 + tid;
      int row = ch >> 3;
      int k8 = ((ch & 7) ^ (row & 7)) << 3;
      const unsigned short* ga = A + (arow0 + row) * 1024 + kt * 64 + k8;
      const unsigned short* gb = B + (brow0 + row) * 1024 + kt * 64 + k8;
      gload_lds16(ga, As + (i * 256 + w * 64) * 8);
      gload_lds16(gb, Bs + (i * 256 + w * 64) * 8);
    }
    __syncthreads();
#pragma unroll
    for (int kf = 0; kf < 2; ++kf) {
      short8 av[4], bv[4];
#pragma unroll
      for (int mf = 0; mf < 4; ++mf) {
        int row = (w >> 1) * 64 + mf * 16 + c;
        int byte = (row * 128 + (kf * 32 + g * 8) * 2) ^ ((row & 7) << 4);
        av[mf] = *(const short8*)((const char*)As + byte);
      }
#pragma unroll
      for (int nf = 0; nf < 4; ++nf) {
        int row = (w & 1) * 64 + nf * 16 + c;
        int byte = (row * 128 + (kf * 32 + g * 8) * 2) ^ ((row & 7) << 4);
        bv[nf] = *(const short8*)((const char*)Bs + byte);
      }
      __builtin_amdgcn_s_setprio(1);
#pragma unroll
      for (int mf = 0; mf < 4; ++mf)
#pragma unroll
        for (int nf = 0; nf < 4; ++nf)
          acc[mf][nf] = __builtin_amdgcn_mfma_f32_16x16x32_bf16(av[mf], bv[nf],
                                                                acc[mf][nf], 0, 0, 0);
      __builtin_amdgcn_s_setprio(0);
    }
  }

  float biasv[4];
#pragma unroll
  for (int nf = 0; nf < 4; ++nf) {
    int n = (int)brow0 + (w & 1) * 64 + nf * 16 + c;
    biasv[nf] = j.bias[n];
  }
  const int smask = (1 << j.sshift) - 1;
  if (j.trans) {
#pragma unroll
    for (int mf = 0; mf < 4; ++mf) {
      int m0 = (int)arow0 + (w >> 1) * 64 + mf * 16 + g * 4;
      int b_ = m0 >> j.sshift;
      int s = (m0 & smask) + j.s_off;
#pragma unroll
      for (int nf = 0; nf < 4; ++nf) {
        int n = (int)brow0 + (w & 1) * 64 + nf * 16 + c;
        int hh = n >> 6, dd = n & 63;
        u16x4 pv;
#pragma unroll
        for (int r = 0; r < 4; ++r)
          pv[r] = f2b((acc[mf][nf][r] + biasv[nf]) * j.scale);
        *(u16x4*)(j.out + (((long)b_ * 16 + hh) * 64 + dd) * 2304 + s) = pv;
      }
    }
  } else {
#pragma unroll
    for (int mf = 0; mf < 4; ++mf) {
#pragma unroll
      for (int r = 0; r < 4; ++r) {
        int m = (int)arow0 + (w >> 1) * 64 + mf * 16 + g * 4 + r;
        int b_ = m >> j.sshift;
        int s = (m & smask) + j.s_off;
#pragma unroll
        for (int nf = 0; nf < 4; ++nf) {
          int n = (int)brow0 + (w & 1) * 64 + nf * 16 + c;
          int hh = n >> 6, dd = n & 63;
          float v = (acc[mf][nf][r] + biasv[nf]) * j.scale;
          j.out[(((long)b_ * 16 + hh) * j.S + s) * 64 + dd] = f2b(v);
        }
      }
    }
  }
}

// ---------------- flash attention (key-split x2, scale-free softmax) ----------
// 1152 blocks (XCD-grouped), 4 waves x 32 q-rows, part = half of the key range.
// P = exp2(st) unnormalized; the common 2^M scale cancels in the merge divide.
__global__ __launch_bounds__(256) void attn_kernel(
    const unsigned short* __restrict__ qw2w, const unsigned short* __restrict__ qw2e,
    const unsigned short* __restrict__ qe2w, const unsigned short* __restrict__ qe2e,
    const unsigned short* __restrict__ Kg, const unsigned short* __restrict__ Vtg,
    float* __restrict__ po0, float* __restrict__ po1, float* __restrict__ lbuf) {
  __shared__ unsigned short smem[16384];  // 32 KiB: K dbuf [0,8KB), Vt dbuf [16KB,32KB)

  const int tid = threadIdx.x;
  const int w = tid >> 6, lane = tid & 63;
  const int l31 = lane & 31, hf = lane >> 5;

  // XCD-grouped bijective remap: 1152 = 8 * 144; work = bh*36 + tile*2 + part
  const int flat = blockIdx.x;
  const int work = (flat & 7) * 144 + (flat >> 3);
  const int part = work & 1;
  const int tile = (work % 36) >> 1;
  const int hb = work / 36;
  const int head = hb & 15, b = hb >> 4;

  const bool isw = tile < 16;
  const int Sq = isw ? 2048 : 256;
  const int q0 = (isw ? tile : tile - 16) * 128 + w * 32;
  const int bh = b * 16 + head;
  const unsigned short* Qa =
      (isw ? qw2w : qe2w) + ((long)bh * Sq + q0 + l31) * 64 + hf * 8;
  const unsigned short* Qb =
      (isw ? qw2e : qe2e) + ((long)bh * Sq + q0 + l31) * 64 + hf * 8;
  const unsigned short* Kb = Kg + (long)bh * 2304 * 64;
  const unsigned short* Vtb = Vtg + (long)bh * 64 * 2304;

  short8 qcur[4];
#pragma unroll
  for (int kf = 0; kf < 4; ++kf) qcur[kf] = *(const short8*)(Qa + kf * 16);

  f32x16 o[2] = {};
  float lrun = 0.f;

  auto stage = [&](int t, int bufi) {
    const unsigned short* Kt = Kb + t * 4096;
    unsigned short* Klp = smem + bufi * 4096;
    unsigned short* Vlp = smem + 8192 + bufi * 4096;
#pragma unroll
    for (int i = 0; i < 2; ++i) {
      int ch = i * 256 + tid;
      int row = ch >> 3, c8 = ch & 7;
      int col = (c8 ^ (row & 7)) << 3;
      gload_lds16(Kt + row * 64 + col, Klp + (i * 256 + (tid & 192)) * 8);
      gload_lds16(Vtb + row * 2304 + t * 64 + col, Vlp + (i * 256 + (tid & 192)) * 8);
    }
  };

  const int t0 = part * 18, t1 = t0 + 18;
  stage(t0, 0);
  __syncthreads();
  int cur = 0;

  for (int t = t0; t < t1; ++t) {
    if (t == 32) {  // entity-key region: switch to the *2e query
#pragma unroll
      for (int kf = 0; kf < 4; ++kf) qcur[kf] = *(const short8*)(Qb + kf * 16);
    }
    if (t + 1 < t1) stage(t + 1, cur ^ 1);

    const char* Kbase = (const char*)(smem + cur * 4096);
    const char* Vbase = (const char*)(smem + 8192 + cur * 4096);

    // QK^T: ST[key][q], 2 key-groups of 32
    f32x16 st[2] = {};
#pragma unroll
    for (int kg = 0; kg < 2; ++kg) {
      int row = kg * 32 + l31;
      int rb = (row * 128) | (hf * 16);
      int sw = (row & 7) << 4;
      short8 kfr[4];
#pragma unroll
      for (int kf = 0; kf < 4; ++kf)
        kfr[kf] = *(const short8*)(Kbase + ((rb + kf * 32) ^ sw));
      __builtin_amdgcn_s_setprio(1);
#pragma unroll
      for (int kf = 0; kf < 4; ++kf) st[kg] = mfma32(kfr[kf], qcur[kf], st[kg]);
      __builtin_amdgcn_s_setprio(0);
    }

    // softmax: P = exp2(st), no max subtraction (scale cancels in merge).
    // 4 independent accumulators break the serial sum chain.
    float s0 = 0.f, s1 = 0.f, s2 = 0.f, s3 = 0.f;
#pragma unroll
    for (int kg = 0; kg < 2; ++kg) {
#pragma unroll
      for (int r = 0; r < 16; r += 4) {
        float p0 = __builtin_amdgcn_exp2f(st[kg][r + 0]);
        float p1 = __builtin_amdgcn_exp2f(st[kg][r + 1]);
        float p2 = __builtin_amdgcn_exp2f(st[kg][r + 2]);
        float p3 = __builtin_amdgcn_exp2f(st[kg][r + 3]);
        st[kg][r + 0] = p0; st[kg][r + 1] = p1;
        st[kg][r + 2] = p2; st[kg][r + 3] = p3;
        s0 += p0; s1 += p1; s2 += p2; s3 += p3;
      }
    }
    lrun += (s0 + s1) + (s2 + s3);

    // P -> bf16 B-frags in-register (cvt_pk + permlane32_swap), PV accumulate
#pragma unroll
    for (int kg = 0; kg < 2; ++kg)
#pragma unroll
      for (int hs = 0; hs < 2; ++hs) {
        const int rbase = hs * 8;
        unsigned int a0 = cvtpk(st[kg][rbase + 0], st[kg][rbase + 1]);
        unsigned int a1 = cvtpk(st[kg][rbase + 2], st[kg][rbase + 3]);
        unsigned int b0 = cvtpk(st[kg][rbase + 4], st[kg][rbase + 5]);
        unsigned int b1 = cvtpk(st[kg][rbase + 6], st[kg][rbase + 7]);
        asm("v_permlane32_swap_b32 %0, %1" : "+v"(a0), "+v"(b0));
        asm("v_permlane32_swap_b32 %0, %1" : "+v"(a1), "+v"(b1));
        u32x4 pw;
        pw[0] = a0; pw[1] = a1; pw[2] = b0; pw[3] = b1;
        short8 pf = __builtin_bit_cast(short8, pw);
        const int ks = kg * 2 + hs;
        short8 vf0, vf1;
        {
          int row = l31;
          int byte = ((row * 128) | (ks * 32 + hf * 16)) ^ ((row & 7) << 4);
          vf0 = *(const short8*)(Vbase + byte);
          row = 32 + l31;
          byte = ((row * 128) | (ks * 32 + hf * 16)) ^ ((row & 7) << 4);
          vf1 = *(const short8*)(Vbase + byte);
        }
        __builtin_amdgcn_s_setprio(1);
        o[0] = mfma32(vf0, pf, o[0]);
        o[1] = mfma32(vf1, pf, o[1]);
        __builtin_amdgcn_s_setprio(0);
      }

    __syncthreads();
    cur ^= 1;
  }

  // epilogue: combine lane halves, write UNNORMALIZED partial o + l
  float ltot = lrun + __shfl_xor(lrun, 32);

  const int sgb = (isw ? 0 : 2048) + q0;
  if (hf == 0) lbuf[(long)part * 73728 + bh * 2304 + sgb + l31] = ltot;

  float* E = (float*)smem + w * 2048;  // 32q x 64d per wave
#pragma unroll
  for (int mf = 0; mf < 2; ++mf)
#pragma unroll
    for (int rg = 0; rg < 4; ++rg) {
      int d0 = mf * 32 + rg * 8 + hf * 4;
      f32x4 v;
      v[0] = o[mf][rg * 4 + 0];
      v[1] = o[mf][rg * 4 + 1];
      v[2] = o[mf][rg * 4 + 2];
      v[3] = o[mf][rg * 4 + 3];
      *(f32x4*)(E + l31 * 64 + (d0 ^ ((l31 & 7) << 2))) = v;
    }

  float* po = part ? po1 : po0;
  float* ob = isw ? po + (((long)b * 2048 + q0) * 1024 + head * 64)
                  : po + (long)2 * 2048 * 1024 +
                        (((long)b * 256 + q0) * 1024 + head * 64);
#pragma unroll
  for (int i = 0; i < 8; ++i) {
    int qr = (lane >> 4) + i * 4;
    int dc = (lane & 15) * 4;
    f32x4 v = *(const f32x4*)(E + qr * 64 + (dc ^ ((qr & 7) << 2)));
    *(f32x4*)(ob + (long)qr * 1024 + dc) = v;
  }
}

// ---------------- merge: out = (o0 + o1) / (l0 + l1) ----------------
__global__ __launch_bounds__(256) void attn_merge(const float* __restrict__ po0,
                                                  const float* __restrict__ po1,
                                                  const float* __restrict__ lbuf,
                                                  float* __restrict__ out) {
  long i = ((long)blockIdx.x * 256 + threadIdx.x) * 4;
  if (i >= 4718592) return;
  int bh, sg;
  if (i < 4194304) {
    int b = (int)(i >> 21), s = (int)((i >> 10) & 2047), h = (int)((i >> 6) & 15);
    bh = b * 16 + h;
    sg = s;
  } else {
    long j = i - 4194304;
    int b = (int)(j >> 18), s = (int)((j >> 10) & 255), h = (int)((j >> 6) & 15);
    bh = b * 16 + h;
    sg = 2048 + s;
  }
  float l0 = lbuf[bh * 2304 + sg];
  float l1 = lbuf[73728 + bh * 2304 + sg];
  f32x4 a = *(const f32x4*)(po0 + i);
  f32x4 c = *(const f32x4*)(po1 + i);
  float inv = 1.f / (l0 + l1);
  f32x4 r = (a + c) * inv;
  *(f32x4*)(out + i) = r;
}

// ---------------- host ----------------
extern "C" void kernel_launch(void* const* d_in, const int* in_sizes, int n_in,
                              void* d_out, int out_size, void* d_ws, size_t ws_size,
                              hipStream_t stream) {
  (void)in_sizes; (void)n_in; (void)out_size; (void)ws_size;
  const float* word = (const float*)d_in[0];
  const float* ent = (const float*)d_in[1];

  char* ws = (char*)d_ws;
  size_t off = 0;
  auto alloc = [&](size_t bytes) {
    void* p = ws + off;
    off += (bytes + 255) & ~(size_t)255;
    return p;
  };
  // NOTE: po0 aliases [Xw, Xe, Wt) (22.0 MB front region) — those are dead by
  // the time attn_kernel writes po0 (all GEMMs complete first, same stream).
  unsigned short* Xw = (unsigned short*)alloc(4096ull * 1024 * 2);
  unsigned short* Xe = (unsigned short*)alloc(512ull * 1024 * 2);
  unsigned short* Wt[6];
  for (int i = 0; i < 6; ++i) Wt[i] = (unsigned short*)alloc(1024ull * 1024 * 2);
  unsigned short* qw2w = (unsigned short*)alloc(2ull * 16 * 2048 * 64 * 2);
  unsigned short* qw2e = (unsigned short*)alloc(2ull * 16 * 2048 * 64 * 2);
  unsigned short* qe2w = (unsigned short*)alloc(2ull * 16 * 256 * 64 * 2);
  unsigned short* qe2e = (unsigned short*)alloc(2ull * 16 * 256 * 64 * 2);
  unsigned short* Kbuf = (unsigned short*)alloc(2ull * 16 * 2304 * 64 * 2);
  unsigned short* Vtbuf = (unsigned short*)alloc(2ull * 16 * 64 * 2304 * 2);
  float* po1 = (float*)alloc(4718592ull * 4);
  float* lbuf = (float*)alloc(2ull * 73728 * 4);
  float* po0 = (float*)ws;  // aliases the dead prepass region

  cvt_f32_bf16<<<2048, 256, 0, stream>>>(word, Xw, 524288);
  cvt_f32_bf16<<<256, 256, 0, stream>>>(ent, Xe, 65536);

  WtransParams wp;
  wp.w[0] = (const float*)d_in[2];   // Wq
  wp.w[1] = (const float*)d_in[4];   // Wk
  wp.w[2] = (const float*)d_in[6];   // Wv
  wp.w[3] = (const float*)d_in[8];   // Ww2e
  wp.w[4] = (const float*)d_in[10];  // We2w
  wp.w[5] = (const float*)d_in[12];  // We2e
  for (int i = 0; i < 6; ++i) wp.wt[i] = Wt[i];
  wtrans<<<dim3(32, 32, 6), dim3(32, 8), 0, stream>>>(wp);

  const float* bq = (const float*)d_in[3];
  const float* bk = (const float*)d_in[5];
  const float* bv = (const float*)d_in[7];
  const float* bw2e = (const float*)d_in[9];
  const float* be2w = (const float*)d_in[11];
  const float* be2e = (const float*)d_in[13];
  const float qs = 0.125f * 1.44269504f;  // 1/sqrt(64) * log2(e): exp2-domain softmax

  Gemm2Params gp;
  gp.Aw = Xw;
  gp.Ae = Xe;
  gp.job[0] = {Wt[0], bq, qw2w, 2048, 0, 11, 0, qs};
  gp.job[1] = {Wt[3], bw2e, qw2e, 2048, 0, 11, 0, qs};
  gp.job[2] = {Wt[1], bk, Kbuf, 2304, 0, 11, 0, 1.f};
  gp.job[3] = {Wt[2], bv, Vtbuf, 2304, 0, 11, 1, 1.f};
  gp.job[4] = {Wt[4], be2w, qe2w, 256, 0, 8, 0, qs};
  gp.job[5] = {Wt[5], be2e, qe2e, 256, 0, 8, 0, qs};
  gp.job[6] = {Wt[1], bk, Kbuf, 2304, 2048, 8, 0, 1.f};
  gp.job[7] = {Wt[2], bv, Vtbuf, 2304, 2048, 8, 1, 1.f};
  gemm_qkv<<<dim3(8, 36, 4), 256, 0, stream>>>(gp);

  attn_kernel<<<1152, 256, 0, stream>>>(qw2w, qw2e, qe2w, qe2e, Kbuf, Vtbuf,
                                        po0, po1, lbuf);
  attn_merge<<<4608, 256, 0, stream>>>(po0, po1, lbuf, (float*)d_out);
}